// Round 2
// baseline (13324.776 us; speedup 1.0000x reference)
//
#include <hip/hip_runtime.h>
#include <hip/hip_bf16.h>

// GRU recurrence B=128, S=512, H=1024 — persistent cooperative kernel.
// 256 WGs (1/CU) x 512 thr. Weights bf16 in LDS (swizzled). 2 grid barriers/step.
//   stage1: [128x2048] = sigmoid(pxi @ [Ww|Uw]^T + b) -> av = r*p + x (bf16), z (f32)
//   stage2: h = tanh(av @ Vw^T + Vb); p = (1-z)p + z h; out[:,t,:] = p; pxi = p + x_{t+1}
// WG (mg,ng): mg=wg>>6 (32 rows), ng=wg&63. stage1 cols ng*32..+32 (of 2048: ng<32 -> r, else z),
// stage2 cols ng*16..+16. Wave wid: mt=wid>>2 (16-row tile), kh=wid&3 (K-quarter, 256).

#define Bb 128
#define Ss 512
#define Hh 1024
#define NWG 256
#define NTHR 512
#define LDS_W2 65536
#define LDS_RED 98304
#define LDS_TOTAL 110592

typedef __bf16 bf16x8 __attribute__((ext_vector_type(8)));
typedef float f32x4 __attribute__((ext_vector_type(4)));

__device__ __forceinline__ float sigmoid_fast(float x) { return 1.0f / (1.0f + __expf(-x)); }
__device__ __forceinline__ float tanh_fast(float x) { return 2.0f / (1.0f + __expf(-2.0f * x)) - 1.0f; }

__device__ __forceinline__ void gbar(unsigned* cnt, unsigned* flag, unsigned ph, int tid) {
    __syncthreads();
    if (tid == 0) {
        unsigned old = __hip_atomic_fetch_add(cnt, 1u, __ATOMIC_ACQ_REL, __HIP_MEMORY_SCOPE_AGENT);
        if (old == ph * (unsigned)NWG - 1u) {
            __hip_atomic_store(flag, ph, __ATOMIC_RELEASE, __HIP_MEMORY_SCOPE_AGENT);
        } else {
            unsigned v;
            do {
                v = __hip_atomic_load(flag, __ATOMIC_RELAXED, __HIP_MEMORY_SCOPE_AGENT);
                if (v < ph) __builtin_amdgcn_s_sleep(1);
            } while (v < ph);
            __builtin_amdgcn_fence(__ATOMIC_ACQUIRE, "agent");
        }
    }
    __syncthreads();
}

__global__ __launch_bounds__(NTHR, 2) void gru_persistent(
    const float* __restrict__ emb, const float* __restrict__ Ww,
    const float* __restrict__ Wb, const float* __restrict__ Uw,
    const float* __restrict__ Ub, const float* __restrict__ Vw,
    const float* __restrict__ Vb,
    float* __restrict__ p, float* __restrict__ z,
    __bf16* __restrict__ pxi, __bf16* __restrict__ av,
    unsigned* cnt, unsigned* flag, float* __restrict__ out)
{
    extern __shared__ char lds[];
    f32x4* red = (f32x4*)(lds + LDS_RED);

    const int tid  = threadIdx.x;
    const int lane = tid & 63;
    const int wid  = tid >> 6;          // 0..7
    const int la   = lane & 15;
    const int lb   = lane >> 4;
    const int wg   = blockIdx.x;        // 0..255
    const int mg   = wg >> 6;           // 0..3
    const int ng   = wg & 63;           // 0..63
    const int mt   = wid >> 2;          // 0..1
    const int kh   = wid & 3;           // 0..3
    const int m0   = mg * 32 + mt * 16;
    const int swz  = (la & 7) << 4;

    // ---- one-time: stage weights fp32->bf16 into LDS with XOR swizzle ----
    {
        const float* src1 = (ng < 32) ? (Ww + (size_t)(ng * 32) * Hh)
                                      : (Uw + (size_t)((ng - 32) * 32) * Hh);
#pragma unroll
        for (int i = 0; i < 8; ++i) {
            int idx = tid + i * NTHR;               // 0..4095
            int r = idx >> 7, g = idx & 127;
            const float* s = src1 + r * Hh + g * 8;
            bf16x8 v;
#pragma unroll
            for (int j = 0; j < 8; ++j) v[j] = (__bf16)s[j];
            *reinterpret_cast<bf16x8*>(lds + r * 2048 + ((g * 16) ^ ((r & 7) << 4))) = v;
        }
        const float* src2 = Vw + (size_t)(ng * 16) * Hh;
#pragma unroll
        for (int i = 0; i < 4; ++i) {
            int idx = tid + i * NTHR;               // 0..2047
            int r = idx >> 7, g = idx & 127;
            const float* s = src2 + r * Hh + g * 8;
            bf16x8 v;
#pragma unroll
            for (int j = 0; j < 8; ++j) v[j] = (__bf16)s[j];
            *reinterpret_cast<bf16x8*>(lds + LDS_W2 + r * 2048 + ((g * 16) ^ ((r & 7) << 4))) = v;
        }
    }
    // ---- one-time: init p=0, pxi = bf16(x_0) over this WG's stage2 slice ----
    {
        int r = tid >> 4, c = tid & 15;
        int brow = mg * 32 + r, col = ng * 16 + c;
        p[brow * Hh + col] = 0.0f;
        pxi[brow * Hh + col] = (__bf16)emb[(size_t)brow * (Ss * Hh) + col];
    }
    unsigned ph = 1;
    gbar(cnt, flag, ph, tid);

    // per-lane invariant addresses
    const __bf16* paA = pxi + (size_t)(m0 + la) * Hh + kh * 256 + lb * 8;
    const __bf16* avA = av  + (size_t)(m0 + la) * Hh + kh * 256 + lb * 8;
    const int j2 = ng * 16 + la;        // stage2 output col

    // hoisted biases (per-lane, constant over t)
    float bias1_0, bias1_1;
    if (ng < 32) { bias1_0 = Wb[ng * 32 + la];        bias1_1 = Wb[ng * 32 + 16 + la]; }
    else         { bias1_0 = Ub[(ng - 32) * 32 + la]; bias1_1 = Ub[(ng - 32) * 32 + 16 + la]; }
    const float bias2 = Vb[j2];

    for (int t = 0; t < Ss; ++t) {
        // ---- prefetch epilogue operands (kh==0 waves only) ----
        f32x4 embn = {0.f,0.f,0.f,0.f}, embc0 = embn, embc1 = embn, pc0 = embn, pc1 = embn;
        if (kh == 0) {
            if (t + 1 < Ss) {
#pragma unroll
                for (int r = 0; r < 4; ++r)
                    embn[r] = emb[((size_t)(m0 + lb * 4 + r) * Ss + (t + 1)) * Hh + j2];
            }
            if (ng < 32) {
                int j1 = ng * 32 + la;
#pragma unroll
                for (int r = 0; r < 4; ++r) {
                    int brow = m0 + lb * 4 + r;
                    embc0[r] = emb[((size_t)brow * Ss + t) * Hh + j1];
                    embc1[r] = emb[((size_t)brow * Ss + t) * Hh + j1 + 16];
                    pc0[r]   = p[brow * Hh + j1];
                    pc1[r]   = p[brow * Hh + j1 + 16];
                }
            }
        }

        // ---- stage1 GEMM: K-quarter, both n-tiles ----
        f32x4 acc0 = {0.f,0.f,0.f,0.f}, acc1 = {0.f,0.f,0.f,0.f};
#pragma unroll
        for (int i = 0; i < 8; ++i) {
            int kb = i * 32;
            bf16x8 a  = *reinterpret_cast<const bf16x8*>(paA + kb);
            int bcol  = ((kh * 256 + kb + lb * 8) * 2) ^ swz;
            bf16x8 b0 = *reinterpret_cast<const bf16x8*>(lds + la * 2048 + bcol);
            bf16x8 b1 = *reinterpret_cast<const bf16x8*>(lds + (16 + la) * 2048 + bcol);
            acc0 = __builtin_amdgcn_mfma_f32_16x16x32_bf16(a, b0, acc0, 0, 0, 0);
            acc1 = __builtin_amdgcn_mfma_f32_16x16x32_bf16(a, b1, acc1, 0, 0, 0);
        }
        if (kh != 0) {
            red[((mt * 2 + 0) * 3 + kh - 1) * 64 + lane] = acc0;
            red[((mt * 2 + 1) * 3 + kh - 1) * 64 + lane] = acc1;
        }
        __syncthreads();
        if (kh == 0) {
#pragma unroll
            for (int s2 = 0; s2 < 3; ++s2) {
                acc0 += red[((mt * 2 + 0) * 3 + s2) * 64 + lane];
                acc1 += red[((mt * 2 + 1) * 3 + s2) * 64 + lane];
            }
            if (ng < 32) {
                int j1 = ng * 32 + la;
#pragma unroll
                for (int r = 0; r < 4; ++r) {
                    int brow = m0 + lb * 4 + r;
                    float rg0 = sigmoid_fast(acc0[r] + bias1_0);
                    float rg1 = sigmoid_fast(acc1[r] + bias1_1);
                    av[brow * Hh + j1]      = (__bf16)(rg0 * pc0[r] + embc0[r]);
                    av[brow * Hh + j1 + 16] = (__bf16)(rg1 * pc1[r] + embc1[r]);
                }
            } else {
                int j1 = (ng - 32) * 32 + la;
#pragma unroll
                for (int r = 0; r < 4; ++r) {
                    int brow = m0 + lb * 4 + r;
                    z[brow * Hh + j1]      = sigmoid_fast(acc0[r] + bias1_0);
                    z[brow * Hh + j1 + 16] = sigmoid_fast(acc1[r] + bias1_1);
                }
            }
        }
        gbar(cnt, flag, ++ph, tid);

        // ---- stage2: prefetch z/p, GEMM over av ----
        f32x4 zc = {0.f,0.f,0.f,0.f}, pold = zc;
        if (kh == 0) {
#pragma unroll
            for (int r = 0; r < 4; ++r) {
                int brow = m0 + lb * 4 + r;
                zc[r]   = z[brow * Hh + j2];
                pold[r] = p[brow * Hh + j2];
            }
        }
        f32x4 acc = {0.f,0.f,0.f,0.f};
#pragma unroll
        for (int i = 0; i < 8; ++i) {
            int kb = i * 32;
            bf16x8 a = *reinterpret_cast<const bf16x8*>(avA + kb);
            int bcol = ((kh * 256 + kb + lb * 8) * 2) ^ swz;
            bf16x8 b = *reinterpret_cast<const bf16x8*>(lds + LDS_W2 + la * 2048 + bcol);
            acc = __builtin_amdgcn_mfma_f32_16x16x32_bf16(a, b, acc, 0, 0, 0);
        }
        if (kh != 0) red[(mt * 3 + kh - 1) * 64 + lane] = acc;
        __syncthreads();
        if (kh == 0) {
#pragma unroll
            for (int s2 = 0; s2 < 3; ++s2) acc += red[(mt * 3 + s2) * 64 + lane];
#pragma unroll
            for (int r = 0; r < 4; ++r) {
                int brow = m0 + lb * 4 + r;
                float h  = tanh_fast(acc[r] + bias2);
                float pn = (1.0f - zc[r]) * pold[r] + zc[r] * h;
                p[brow * Hh + j2] = pn;
                out[((size_t)brow * Ss + t) * Hh + j2] = pn;
                if (t + 1 < Ss) pxi[brow * Hh + j2] = (__bf16)(pn + embn[r]);
            }
        }
        if (t + 1 < Ss) gbar(cnt, flag, ++ph, tid);
    }
}

// ---- launch -----------------------------------------------------------------

extern "C" void kernel_launch(void* const* d_in, const int* in_sizes, int n_in,
                              void* d_out, int out_size, void* d_ws, size_t ws_size,
                              hipStream_t stream) {
    const float* emb = (const float*)d_in[0];
    const float* Ww  = (const float*)d_in[1];
    const float* Wb  = (const float*)d_in[2];
    const float* Uw  = (const float*)d_in[3];
    const float* Ub  = (const float*)d_in[4];
    const float* Vw  = (const float*)d_in[5];
    const float* Vb  = (const float*)d_in[6];
    float* out = (float*)d_out;

    char* ws = (char*)d_ws;
    float*    p    = (float*)(ws);                               // 512 KB
    float*    zbuf = (float*)(ws + 512 * 1024);                  // 512 KB
    __bf16*   pxi  = (__bf16*)(ws + 1024 * 1024);                // 256 KB
    __bf16*   av   = (__bf16*)(ws + 1024 * 1024 + 256 * 1024);   // 256 KB
    unsigned* barr = (unsigned*)(ws + 1536 * 1024);
    unsigned* cnt  = barr;
    unsigned* flag = barr + 32;                                  // separate cacheline

    hipMemsetAsync(barr, 0, 256, stream);
    hipFuncSetAttribute(reinterpret_cast<const void*>(gru_persistent),
                        hipFuncAttributeMaxDynamicSharedMemorySize, LDS_TOTAL);

    void* args[] = {(void*)&emb, (void*)&Ww, (void*)&Wb, (void*)&Uw, (void*)&Ub,
                    (void*)&Vw, (void*)&Vb, (void*)&p, (void*)&zbuf, (void*)&pxi,
                    (void*)&av, (void*)&cnt, (void*)&flag, (void*)&out};
    hipError_t e = hipLaunchCooperativeKernel(
        reinterpret_cast<const void*>(gru_persistent), dim3(NWG), dim3(NTHR),
        args, LDS_TOTAL, stream);
    if (e != hipSuccess) {
        // 256 WGs with 108KB LDS force 1 WG/CU on 256 CUs -> co-resident anyway.
        gru_persistent<<<dim3(NWG), dim3(NTHR), LDS_TOTAL, stream>>>(
            emb, Ww, Wb, Uw, Ub, Vw, Vb, p, zbuf, pxi, av, cnt, flag, out);
    }
}

// Round 3
// 11326.381 us; speedup vs baseline: 1.1764x; 1.1764x over previous
//
#include <hip/hip_runtime.h>
#include <hip/hip_bf16.h>

// GRU recurrence B=128, S=512, H=1024.
// 8 INDEPENDENT groups of 32 WGs (group = wg&7 -> XCD-local under round-robin,
// correctness does not depend on placement). Group owns 16 batch rows.
// Weights live in REGISTERS (24 bf16x8 frags/wave; group's 256 waves = all 6MB).
// Phase A: r = sigmoid(pxi@Ww^T+Wb) [waves 0-3], z = sigmoid(pxi@Uw^T+Ub) [waves 4-7]
//          -> av = r*p + x (bf16, global);  z stays in registers of waves 4,5.
// Phase B: h = tanh(av@Vw^T+Vb) [all 8 waves, 4-way K-split];
//          p' = (1-z)p + z h; out[:,t,:] = p'; pxi' = bf16(p' + x_{t+1}).
// 2 group barriers/step, distributed-slot (release store + poll + acquire fence).

#define Ss 512
#define Hh 1024
#define NWG 256
#define NTHR 512

typedef __bf16 bf16x8 __attribute__((ext_vector_type(8)));
typedef float f32x4 __attribute__((ext_vector_type(4)));

__device__ __forceinline__ float sigmoid_fast(float x) { return 1.0f / (1.0f + __expf(-x)); }
__device__ __forceinline__ float tanh_fast(float x) { return 2.0f / (1.0f + __expf(-2.0f * x)) - 1.0f; }

// group barrier: 32 distributed slots, wave 0 polls, monotonic phase
__device__ __forceinline__ void gbar(unsigned* slots, unsigned ph, int tid, int lw) {
    __syncthreads();
    if (tid == 0)
        __hip_atomic_store(&slots[lw], ph, __ATOMIC_RELEASE, __HIP_MEMORY_SCOPE_AGENT);
    if (tid < 64) {
        for (;;) {
            unsigned v = __hip_atomic_load(&slots[tid & 31], __ATOMIC_RELAXED,
                                           __HIP_MEMORY_SCOPE_AGENT);
            if (__all((int)(v >= ph))) break;
            __builtin_amdgcn_s_sleep(1);
        }
        __builtin_amdgcn_fence(__ATOMIC_ACQUIRE, "agent");
    }
    __syncthreads();
}

__global__ __launch_bounds__(NTHR, 2) void gru_grouped(
    const float* __restrict__ emb, const float* __restrict__ Ww,
    const float* __restrict__ Wb, const float* __restrict__ Uw,
    const float* __restrict__ Ub, const float* __restrict__ Vw,
    const float* __restrict__ Vb,
    float* __restrict__ p, __bf16* __restrict__ pxi, __bf16* __restrict__ av,
    unsigned* __restrict__ arr, float* __restrict__ out)
{
    __shared__ f32x4 sc[6][64];

    const int tid   = threadIdx.x;
    const int lane  = tid & 63;
    const int wid   = tid >> 6;          // 0..7
    const int la    = lane & 15;
    const int lb    = lane >> 4;
    const int wg    = blockIdx.x;
    const int g     = wg & 7;            // group (XCD under round-robin)
    const int lw    = wg >> 3;           // 0..31 within group
    const int rbase = g * 16;            // 16 batch rows per group
    const int n0    = lw * 32;           // 32 output cols per WG
    const int nt    = wid & 1;           // n-tile (16 cols)
    const int kh    = (wid >> 1) & 1;    // phase A K-half (512)
    const int kq    = wid >> 1;          // phase B K-quarter (256)
    const int jc    = n0 + nt * 16 + la; // this lane's output column
    unsigned* slots = arr + g * 32;

    // ---- weights -> registers (one-time) ----
    // Phase A B-frags: waves 0-3 from Ww (r), waves 4-7 from Uw (z). K-half kh.
    const float* WA = (wid < 4) ? Ww : Uw;
    bf16x8 Wa[16];
#pragma unroll
    for (int i = 0; i < 16; ++i) {
        const float* s = WA + (size_t)jc * Hh + kh * 512 + i * 32 + lb * 8;
        bf16x8 v;
#pragma unroll
        for (int j = 0; j < 8; ++j) v[j] = (__bf16)s[j];
        Wa[i] = v;
    }
    // Phase B B-frags: Vw, K-quarter kq.
    bf16x8 Vf[8];
#pragma unroll
    for (int i = 0; i < 8; ++i) {
        const float* s = Vw + (size_t)jc * Hh + kq * 256 + i * 32 + lb * 8;
        bf16x8 v;
#pragma unroll
        for (int j = 0; j < 8; ++j) v[j] = (__bf16)s[j];
        Vf[i] = v;
    }
    const float bias1 = (wid < 4) ? Wb[jc] : Ub[jc];
    const float bias2 = Vb[jc];

    // ---- init p=0, pxi = bf16(x_0) over this WG's 16x32 slice ----
    {
        int row = rbase + (tid >> 5);
        int col = n0 + (tid & 31);
        p[row * Hh + col] = 0.0f;
        pxi[row * Hh + col] = (__bf16)emb[(size_t)row * Ss * Hh + col];
    }
    unsigned ph = 1;
    gbar(slots, ph, tid, lw);

    const __bf16* aA = pxi + (size_t)(rbase + la) * Hh + kh * 512 + lb * 8;
    const __bf16* aB = av  + (size_t)(rbase + la) * Hh + kq * 256 + lb * 8;

    for (int t = 0; t < Ss; ++t) {
        // ---- prefetch epilogue operands ----
        f32x4 embc = {0.f,0.f,0.f,0.f}, pc = embc, embn = embc, pold = embc, zz = embc;
        if (wid == 0 || wid == 1) {
#pragma unroll
            for (int r = 0; r < 4; ++r) {
                int row = rbase + lb * 4 + r;
                embc[r] = emb[((size_t)row * Ss + t) * Hh + jc];
                pc[r]   = p[row * Hh + jc];
            }
        } else if (wid == 4 || wid == 5) {
#pragma unroll
            for (int r = 0; r < 4; ++r) {
                int row = rbase + lb * 4 + r;
                pold[r] = p[row * Hh + jc];
                if (t + 1 < Ss)
                    embn[r] = emb[((size_t)row * Ss + (t + 1)) * Hh + jc];
            }
        }

        // ---- phase A: r-GEMM (waves 0-3) / z-GEMM (waves 4-7), K-half each ----
        f32x4 acc0 = {0.f,0.f,0.f,0.f}, acc1 = acc0;
#pragma unroll
        for (int i = 0; i < 8; ++i) {
            bf16x8 a0 = *reinterpret_cast<const bf16x8*>(aA + (2 * i) * 32);
            bf16x8 a1 = *reinterpret_cast<const bf16x8*>(aA + (2 * i + 1) * 32);
            acc0 = __builtin_amdgcn_mfma_f32_16x16x32_bf16(a0, Wa[2 * i],     acc0, 0, 0, 0);
            acc1 = __builtin_amdgcn_mfma_f32_16x16x32_bf16(a1, Wa[2 * i + 1], acc1, 0, 0, 0);
        }
        f32x4 acc = acc0 + acc1;
        if (kh == 1) sc[(wid < 4 ? 0 : 2) + nt][lane] = acc;   // partials: wid2,3,6,7
        __syncthreads();
        if (wid == 0 || wid == 1) {            // r-finalize -> av
            acc += sc[nt][lane];
#pragma unroll
            for (int r = 0; r < 4; ++r) {
                int row = rbase + lb * 4 + r;
                float rg = sigmoid_fast(acc[r] + bias1);
                av[row * Hh + jc] = (__bf16)(rg * pc[r] + embc[r]);
            }
        } else if (wid == 4 || wid == 5) {     // z-finalize -> registers
            acc += sc[2 + nt][lane];
#pragma unroll
            for (int r = 0; r < 4; ++r) zz[r] = sigmoid_fast(acc[r] + bias1);
        }
        gbar(slots, ++ph, tid, lw);            // publish av

        // ---- phase B: h-GEMM, all 8 waves, K-quarter each ----
        f32x4 h0 = {0.f,0.f,0.f,0.f}, h1 = h0;
#pragma unroll
        for (int i = 0; i < 4; ++i) {
            bf16x8 a0 = *reinterpret_cast<const bf16x8*>(aB + (2 * i) * 32);
            bf16x8 a1 = *reinterpret_cast<const bf16x8*>(aB + (2 * i + 1) * 32);
            h0 = __builtin_amdgcn_mfma_f32_16x16x32_bf16(a0, Vf[2 * i],     h0, 0, 0, 0);
            h1 = __builtin_amdgcn_mfma_f32_16x16x32_bf16(a1, Vf[2 * i + 1], h1, 0, 0, 0);
        }
        f32x4 hacc = h0 + h1;
        if (wid != 4 && wid != 5)
            sc[nt * 3 + (kq == 0 ? 0 : (kq == 1 ? 1 : 2))][lane] = hacc;
        __syncthreads();
        if (wid == 4 || wid == 5) {            // h-finalize + gate combine
            int base = nt * 3;
            hacc += sc[base][lane] + sc[base + 1][lane] + sc[base + 2][lane];
#pragma unroll
            for (int r = 0; r < 4; ++r) {
                int row  = rbase + lb * 4 + r;
                float h  = tanh_fast(hacc[r] + bias2);
                float pn = (1.0f - zz[r]) * pold[r] + zz[r] * h;
                p[row * Hh + jc] = pn;
                out[((size_t)row * Ss + t) * Hh + jc] = pn;
                if (t + 1 < Ss)
                    pxi[row * Hh + jc] = (__bf16)(pn + embn[r]);
            }
        }
        if (t + 1 < Ss) gbar(slots, ++ph, tid, lw);   // publish p, pxi
    }
}

// ---- launch -----------------------------------------------------------------

extern "C" void kernel_launch(void* const* d_in, const int* in_sizes, int n_in,
                              void* d_out, int out_size, void* d_ws, size_t ws_size,
                              hipStream_t stream) {
    const float* emb = (const float*)d_in[0];
    const float* Ww  = (const float*)d_in[1];
    const float* Wb  = (const float*)d_in[2];
    const float* Uw  = (const float*)d_in[3];
    const float* Ub  = (const float*)d_in[4];
    const float* Vw  = (const float*)d_in[5];
    const float* Vb  = (const float*)d_in[6];
    float* out = (float*)d_out;

    char* ws = (char*)d_ws;
    float*    p    = (float*)(ws);                                 // 512 KB
    __bf16*   pxi  = (__bf16*)(ws + 512 * 1024);                   // 256 KB
    __bf16*   av   = (__bf16*)(ws + 768 * 1024);                   // 256 KB
    unsigned* arr  = (unsigned*)(ws + 1024 * 1024);                // 1 KB (8 groups x 32)

    hipMemsetAsync(arr, 0, 1024, stream);

    void* args[] = {(void*)&emb, (void*)&Ww, (void*)&Wb, (void*)&Uw, (void*)&Ub,
                    (void*)&Vw, (void*)&Vb, (void*)&p, (void*)&pxi, (void*)&av,
                    (void*)&arr, (void*)&out};
    hipError_t e = hipLaunchCooperativeKernel(
        reinterpret_cast<const void*>(gru_grouped), dim3(NWG), dim3(NTHR),
        args, 0, stream);
    if (e != hipSuccess) {
        gru_grouped<<<dim3(NWG), dim3(NTHR), 0, stream>>>(
            emb, Ww, Wb, Uw, Ub, Vw, Vb, p, pxi, av, arr, out);
    }
}

// Round 4
// 3063.356 us; speedup vs baseline: 4.3497x; 3.6974x over previous
//
#include <hip/hip_runtime.h>
#include <hip/hip_bf16.h>

// GRU recurrence B=128, S=512, H=1024 — persistent kernel, IC-coherent exchange.
// 8 independent groups x 32 WGs; group owns 16 batch rows; WG owns 32 cols.
// Weights in registers (verified layout from round 3). Cross-WG data (pxi, av,
// barrier slots) uses sc0+sc1 (L1+L2-bypass, Infinity-Cache-coherent) loads /
// stores -> NO agent fences, NO L2 writeback/invalidate per phase.
// p lives in registers (col-owner waves 4,5) + LDS mirror for waves 0,1.
// Per phase each WG stages the group's 16x1024 bf16 activation tile (32 KB)
// from IC into LDS (XOR-swizzled), then ds_reads MFMA fragments.

#define Ss 512
#define Hh 1024
#define NWG 256
#define NTHR 512

typedef __bf16 bf16x8 __attribute__((ext_vector_type(8)));
typedef float f32x4 __attribute__((ext_vector_type(4)));
typedef int   i32x4 __attribute__((ext_vector_type(4)));

__device__ __forceinline__ float sigmoid_fast(float x) { return 1.0f / (1.0f + __expf(-x)); }
__device__ __forceinline__ float tanh_fast(float x) { return 2.0f / (1.0f + __expf(-2.0f * x)) - 1.0f; }

// 2-byte store, coherent at IC (bypass L1+L2)
__device__ __forceinline__ void ic_store_bf16(__bf16* p, float v) {
    unsigned u = (unsigned)__builtin_bit_cast(unsigned short, (__bf16)v);
    asm volatile("global_store_short %0, %1, off sc0 sc1" :: "v"(p), "v"(u) : "memory");
}

// stage a [16 x 1024] bf16 tile (row stride 2048B) from IC into LDS, swizzled.
// All 512 threads participate: 4 x 16B chunks each.
__device__ __forceinline__ void stage16rows(const char* g, char* stbuf, int tid) {
    int c0 = tid, c1 = tid + 512, c2 = tid + 1024, c3 = tid + 1536;
    const void* a0 = g + (c0 >> 7) * 2048 + (c0 & 127) * 16;
    const void* a1 = g + (c1 >> 7) * 2048 + (c1 & 127) * 16;
    const void* a2 = g + (c2 >> 7) * 2048 + (c2 & 127) * 16;
    const void* a3 = g + (c3 >> 7) * 2048 + (c3 & 127) * 16;
    i32x4 r0, r1, r2, r3;
    asm volatile(
        "global_load_dwordx4 %0, %4, off sc0 sc1\n\t"
        "global_load_dwordx4 %1, %5, off sc0 sc1\n\t"
        "global_load_dwordx4 %2, %6, off sc0 sc1\n\t"
        "global_load_dwordx4 %3, %7, off sc0 sc1\n\t"
        "s_waitcnt vmcnt(0)"
        : "=&v"(r0), "=&v"(r1), "=&v"(r2), "=&v"(r3)
        : "v"(a0), "v"(a1), "v"(a2), "v"(a3));
    *(i32x4*)(stbuf + (c0 >> 7) * 2048 + (((c0 & 127) * 16) ^ (((c0 >> 7) & 7) << 4))) = r0;
    *(i32x4*)(stbuf + (c1 >> 7) * 2048 + (((c1 & 127) * 16) ^ (((c1 >> 7) & 7) << 4))) = r1;
    *(i32x4*)(stbuf + (c2 >> 7) * 2048 + (((c2 & 127) * 16) ^ (((c2 >> 7) & 7) << 4))) = r2;
    *(i32x4*)(stbuf + (c3 >> 7) * 2048 + (((c3 & 127) * 16) ^ (((c3 >> 7) & 7) << 4))) = r3;
}

__device__ __forceinline__ bf16x8 frag(const char* stbuf, int row, int kelem) {
    return *(const bf16x8*)(stbuf + row * 2048 + ((kelem * 2) ^ ((row & 7) << 4)));
}

// group barrier: per-wave vmcnt drain -> syncthreads (all stores acked) ->
// slot store (sc0sc1) -> wave0 polls 32 slots at IC -> syncthreads.
__device__ __forceinline__ void gbar(unsigned* slots, unsigned ph, int tid, int lw) {
    asm volatile("s_waitcnt vmcnt(0)" ::: "memory");
    __syncthreads();
    if (tid == 0)
        __hip_atomic_store(&slots[lw * 16], ph, __ATOMIC_RELAXED, __HIP_MEMORY_SCOPE_SYSTEM);
    if (tid < 64) {
        for (;;) {
            unsigned v = __hip_atomic_load(&slots[(tid & 31) * 16], __ATOMIC_RELAXED,
                                           __HIP_MEMORY_SCOPE_SYSTEM);
            if (__all((int)(v >= ph))) break;
            __builtin_amdgcn_s_sleep(2);
        }
    }
    __syncthreads();
}

__global__ __launch_bounds__(NTHR, 2) void gru_ic(
    const float* __restrict__ emb, const float* __restrict__ Ww,
    const float* __restrict__ Wb, const float* __restrict__ Uw,
    const float* __restrict__ Ub, const float* __restrict__ Vw,
    const float* __restrict__ Vb,
    __bf16* __restrict__ pxi, __bf16* __restrict__ av,
    unsigned* __restrict__ arr, float* __restrict__ out)
{
    __shared__ char  stbuf[32768];
    __shared__ f32x4 sc[6][64];
    __shared__ float p_lds[16][32];

    const int tid   = threadIdx.x;
    const int lane  = tid & 63;
    const int wid   = tid >> 6;          // 0..7
    const int la    = lane & 15;
    const int lb    = lane >> 4;
    const int wg    = blockIdx.x;
    const int g     = wg & 7;            // group
    const int lw    = wg >> 3;           // 0..31 within group
    const int rbase = g * 16;            // group's 16 batch rows
    const int n0    = lw * 32;           // WG's 32 output cols
    const int nt    = wid & 1;           // n-tile (16 cols)
    const int kh    = (wid >> 1) & 1;    // phase A K-half
    const int kq    = wid >> 1;          // phase B K-quarter
    const int jc    = n0 + nt * 16 + la;
    unsigned* slots = arr + g * 512;     // 32 slots x 64B stride

    // ---- weights -> registers (one-time; layout verified in round 3) ----
    const float* WA = (wid < 4) ? Ww : Uw;
    bf16x8 Wa[16];
#pragma unroll
    for (int i = 0; i < 16; ++i) {
        const float* s = WA + (size_t)jc * Hh + kh * 512 + i * 32 + lb * 8;
        bf16x8 v;
#pragma unroll
        for (int j = 0; j < 8; ++j) v[j] = (__bf16)s[j];
        Wa[i] = v;
    }
    bf16x8 Vf[8];
#pragma unroll
    for (int i = 0; i < 8; ++i) {
        const float* s = Vw + (size_t)jc * Hh + kq * 256 + i * 32 + lb * 8;
        bf16x8 v;
#pragma unroll
        for (int j = 0; j < 8; ++j) v[j] = (__bf16)s[j];
        Vf[i] = v;
    }
    const float bias1 = (wid < 4) ? Wb[jc] : Ub[jc];
    const float bias2 = Vb[jc];

    // ---- init: p = 0 (regs + LDS mirror), pxi0 = bf16(x_0) via IC stores ----
    ((float*)p_lds)[tid] = 0.0f;
    f32x4 pregs = {0.f, 0.f, 0.f, 0.f};
    if (wid == 4 || wid == 5) {
#pragma unroll
        for (int r = 0; r < 4; ++r) {
            int row = rbase + lb * 4 + r;
            ic_store_bf16(pxi + row * Hh + jc, emb[(size_t)row * (Ss * Hh) + jc]);
        }
    }
    unsigned ph = 1;
    gbar(slots, ph, tid, lw);

    const char* pxiG = (const char*)(pxi + (size_t)rbase * Hh);
    const char* avG  = (const char*)(av  + (size_t)rbase * Hh);

    for (int t = 0; t < Ss; ++t) {
        // ---- prefetch epilogue operands (normal cached loads, read-only) ----
        f32x4 embc = {0.f,0.f,0.f,0.f}, embn = embc, zz = embc;
        if (wid == 0 || wid == 1) {
#pragma unroll
            for (int r = 0; r < 4; ++r)
                embc[r] = emb[((size_t)(rbase + lb * 4 + r) * Ss + t) * Hh + jc];
        } else if ((wid == 4 || wid == 5) && t + 1 < Ss) {
#pragma unroll
            for (int r = 0; r < 4; ++r)
                embn[r] = emb[((size_t)(rbase + lb * 4 + r) * Ss + (t + 1)) * Hh + jc];
        }

        // ---- phase A: stage pxi -> LDS, GEMM (r: wid0-3, z: wid4-7) ----
        stage16rows(pxiG, stbuf, tid);
        __syncthreads();
        f32x4 acc0 = {0.f,0.f,0.f,0.f}, acc1 = acc0;
#pragma unroll
        for (int i = 0; i < 8; ++i) {
            bf16x8 a0 = frag(stbuf, la, kh * 512 + (2 * i) * 32 + lb * 8);
            bf16x8 a1 = frag(stbuf, la, kh * 512 + (2 * i + 1) * 32 + lb * 8);
            acc0 = __builtin_amdgcn_mfma_f32_16x16x32_bf16(a0, Wa[2 * i],     acc0, 0, 0, 0);
            acc1 = __builtin_amdgcn_mfma_f32_16x16x32_bf16(a1, Wa[2 * i + 1], acc1, 0, 0, 0);
        }
        f32x4 acc = acc0 + acc1;
        if (kh == 1) sc[(wid < 4 ? 0 : 2) + nt][lane] = acc;
        __syncthreads();
        if (wid == 0 || wid == 1) {          // r-finalize -> av (IC store)
            acc += sc[nt][lane];
#pragma unroll
            for (int r = 0; r < 4; ++r) {
                int row = rbase + lb * 4 + r;
                float rg = sigmoid_fast(acc[r] + bias1);
                float pc = p_lds[lb * 4 + r][nt * 16 + la];
                ic_store_bf16(av + row * Hh + jc, rg * pc + embc[r]);
            }
        } else if (wid == 4 || wid == 5) {   // z-finalize -> registers
            acc += sc[2 + nt][lane];
#pragma unroll
            for (int r = 0; r < 4; ++r) zz[r] = sigmoid_fast(acc[r] + bias1);
        }
        gbar(slots, ++ph, tid, lw);          // publish av

        // ---- phase B: stage av -> LDS, h-GEMM (all waves, K-quarter) ----
        stage16rows(avG, stbuf, tid);
        __syncthreads();
        f32x4 h0 = {0.f,0.f,0.f,0.f}, h1 = h0;
#pragma unroll
        for (int i = 0; i < 4; ++i) {
            bf16x8 a0 = frag(stbuf, la, kq * 256 + (2 * i) * 32 + lb * 8);
            bf16x8 a1 = frag(stbuf, la, kq * 256 + (2 * i + 1) * 32 + lb * 8);
            h0 = __builtin_amdgcn_mfma_f32_16x16x32_bf16(a0, Vf[2 * i],     h0, 0, 0, 0);
            h1 = __builtin_amdgcn_mfma_f32_16x16x32_bf16(a1, Vf[2 * i + 1], h1, 0, 0, 0);
        }
        f32x4 hacc = h0 + h1;
        if (wid != 4 && wid != 5)
            sc[nt * 3 + (kq == 0 ? 0 : (kq == 1 ? 1 : 2))][lane] = hacc;
        __syncthreads();
        if (wid == 4 || wid == 5) {          // h-finalize + gate combine
            int base = nt * 3;
            hacc += sc[base][lane] + sc[base + 1][lane] + sc[base + 2][lane];
#pragma unroll
            for (int r = 0; r < 4; ++r) {
                int row  = rbase + lb * 4 + r;
                float h  = tanh_fast(hacc[r] + bias2);
                float pn = (1.0f - zz[r]) * pregs[r] + zz[r] * h;
                pregs[r] = pn;
                p_lds[lb * 4 + r][nt * 16 + la] = pn;
                out[((size_t)row * Ss + t) * Hh + jc] = pn;   // normal cached store
                if (t + 1 < Ss)
                    ic_store_bf16(pxi + row * Hh + jc, pn + embn[r]);
            }
        }
        if (t + 1 < Ss) gbar(slots, ++ph, tid, lw);   // publish pxi
    }
}

// ---- launch -----------------------------------------------------------------

extern "C" void kernel_launch(void* const* d_in, const int* in_sizes, int n_in,
                              void* d_out, int out_size, void* d_ws, size_t ws_size,
                              hipStream_t stream) {
    const float* emb = (const float*)d_in[0];
    const float* Ww  = (const float*)d_in[1];
    const float* Wb  = (const float*)d_in[2];
    const float* Uw  = (const float*)d_in[3];
    const float* Ub  = (const float*)d_in[4];
    const float* Vw  = (const float*)d_in[5];
    const float* Vb  = (const float*)d_in[6];
    float* out = (float*)d_out;

    char* ws = (char*)d_ws;
    __bf16*   pxi = (__bf16*)(ws);                     // 256 KB
    __bf16*   av  = (__bf16*)(ws + 256 * 1024);        // 256 KB
    unsigned* arr = (unsigned*)(ws + 512 * 1024);      // 16 KB (8 groups x 32 slots x 64B)

    hipMemsetAsync(arr, 0, 16384, stream);

    void* args[] = {(void*)&emb, (void*)&Ww, (void*)&Wb, (void*)&Uw, (void*)&Ub,
                    (void*)&Vw, (void*)&Vb, (void*)&pxi, (void*)&av,
                    (void*)&arr, (void*)&out};
    hipError_t e = hipLaunchCooperativeKernel(
        reinterpret_cast<const void*>(gru_ic), dim3(NWG), dim3(NTHR),
        args, 0, stream);
    if (e != hipSuccess) {
        gru_ic<<<dim3(NWG), dim3(NTHR), 0, stream>>>(
            emb, Ww, Wb, Uw, Ub, Vw, Vb, pxi, av, arr, out);
    }
}